// Round 5
// baseline (808.144 us; speedup 1.0000x reference)
//
#include <hip/hip_runtime.h>
#include <stdint.h>

// Problem constants (Attention_39556648796173)
// Inputs: float32 buffers (per reference dtypes). Output: float32.
// Compute core: bf16 MFMA (comparison tolerance is bf16-scaled: 2% of max).
#define TTOK  8192
#define DIMM  2048
#define NH    16
#define NKV   8
#define HD    128
#define SEQ   1024
#define BATCH 8
#define BLKSZ 16

typedef unsigned short u16;
typedef __attribute__((ext_vector_type(8))) short bfrag;   // 8 x bf16 (4 VGPRs)
typedef __attribute__((ext_vector_type(4))) float f32x4;   // MFMA accumulator

__device__ __forceinline__ float bf2f(u16 u) {
  unsigned int v = ((unsigned int)u) << 16;
  float f; __builtin_memcpy(&f, &v, 4); return f;
}
__device__ __forceinline__ u16 f2bf(float f) {
  unsigned int v; __builtin_memcpy(&v, &f, 4);
  v = v + 0x7FFFu + ((v >> 16) & 1u);   // RNE
  return (u16)(v >> 16);
}

// async global->LDS, 16B per lane; LDS dest = wave-uniform base + lane*16
__device__ __forceinline__ void gll16(const void* g, void* l) {
  __builtin_amdgcn_global_load_lds(
      (__attribute__((address_space(1))) void*)(g),
      (__attribute__((address_space(3))) void*)(l), 16, 0, 0);
}
// full drain (vmcnt=0, expcnt=0, lgkmcnt=0) + compiler memory fence
__device__ __forceinline__ void hard_fence() {
  asm volatile("" ::: "memory");
  __builtin_amdgcn_s_waitcnt(0);
  asm volatile("" ::: "memory");
}

// ---------------------------------------------------------------------------
// fp32 -> bf16 bulk convert (n multiple of 2048); 8 elems/thread
// ---------------------------------------------------------------------------
__global__ __launch_bounds__(256) void f32_to_bf16(const float* __restrict__ in,
                                                   u16* __restrict__ out, size_t n) {
  size_t i = ((size_t)blockIdx.x * 256 + threadIdx.x) * 8;
  if (i >= n) return;
  float4 a = *(const float4*)(in + i);
  float4 b = *(const float4*)(in + i + 4);
  union { u16 o[8]; uint4 v; } u;
  u.o[0] = f2bf(a.x); u.o[1] = f2bf(a.y); u.o[2] = f2bf(a.z); u.o[3] = f2bf(a.w);
  u.o[4] = f2bf(b.x); u.o[5] = f2bf(b.y); u.o[6] = f2bf(b.z); u.o[7] = f2bf(b.w);
  *(uint4*)(out + i) = u.v;
}

// ---------------------------------------------------------------------------
// Tiled transpose + fp32->bf16: out[n][k] = bf16(in[k][n]), K,N multiples of 64
// ---------------------------------------------------------------------------
__global__ __launch_bounds__(256) void ktranspose_f(const float* __restrict__ in,
                                                    u16* __restrict__ out, int K, int N) {
  __shared__ __align__(16) u16 tile[64 * 65];
  int n0 = blockIdx.x * 64, k0 = blockIdx.y * 64;
  int tx = threadIdx.x & 63, ty = threadIdx.x >> 6;
  for (int r = 0; r < 16; ++r) {
    int kk = r * 4 + ty;
    tile[kk * 65 + tx] = f2bf(in[(size_t)(k0 + kk) * N + n0 + tx]);
  }
  __syncthreads();
  for (int r = 0; r < 16; ++r) {
    int nn = r * 4 + ty;
    out[(size_t)(n0 + nn) * K + k0 + tx] = tile[tx * 65 + nn];
  }
}

// ---------------------------------------------------------------------------
// m97-style GEMM: C[M,N] = A[M,K] @ B, with B given transposed (Bt[N,K]).
// 128x128 tile, BK=32, 4 waves (2x2 of 64x64), mfma 16x16x32 bf16.
// Hardened: explicit full s_waitcnt + compiler fences around staging so the
// async DMA can never be scheduled across a barrier or left undrained.
// ---------------------------------------------------------------------------
template <typename OutT>
__global__ __launch_bounds__(256) void gemm_bt(const u16* __restrict__ A,
                                               const u16* __restrict__ Bt,
                                               OutT* __restrict__ C,
                                               int M, int N, int K) {
  __shared__ __align__(16) u16 As[128 * 32];
  __shared__ __align__(16) u16 Bs[128 * 32];
  int tid = threadIdx.x;
  int wave = tid >> 6, lane = tid & 63, quad = lane >> 4, l15 = lane & 15;
  int m0 = blockIdx.y * 128, n0 = blockIdx.x * 128;
  int wm = (wave >> 1) * 64, wn = (wave & 1) * 64;

  f32x4 acc[4][4];
  for (int i = 0; i < 4; ++i)
    for (int j = 0; j < 4; ++j) acc[i][j] = (f32x4){0.f, 0.f, 0.f, 0.f};

  // staging decode: straight mapping (granule g -> row g>>2, k-granule g&3)
  int g0 = wave * 64 + lane;            // granules 0..255
  int g1 = 256 + wave * 64 + lane;      // granules 256..511
  const u16* Arow0 = A + (size_t)(m0 + (g0 >> 2)) * K + (g0 & 3) * 8;
  const u16* Arow1 = A + (size_t)(m0 + (g1 >> 2)) * K + (g1 & 3) * 8;
  const u16* Brow0 = Bt + (size_t)(n0 + (g0 >> 2)) * K + (g0 & 3) * 8;
  const u16* Brow1 = Bt + (size_t)(n0 + (g1 >> 2)) * K + (g1 & 3) * 8;
  char* AsB = (char*)As;
  char* BsB = (char*)Bs;
  int lds0 = wave * 1024, lds1 = 4096 + wave * 1024;  // wave-uniform bases

  for (int k0 = 0; k0 < K; k0 += 32) {
    __syncthreads();                 // all waves done reading previous tile
    asm volatile("" ::: "memory");   // no staging op may move above this point
    gll16(Arow0 + k0, AsB + lds0);
    gll16(Arow1 + k0, AsB + lds1);
    gll16(Brow0 + k0, BsB + lds0);
    gll16(Brow1 + k0, BsB + lds1);
    hard_fence();                    // own DMA fully landed in LDS
    __syncthreads();                 // everyone's DMA landed

    bfrag af[4], bfv[4];
    for (int im = 0; im < 4; ++im) {
      int m = wm + im * 16 + l15;
      af[im] = *(const bfrag*)(AsB + m * 64 + quad * 16);
    }
    for (int jn = 0; jn < 4; ++jn) {
      int n = wn + jn * 16 + l15;
      bfv[jn] = *(const bfrag*)(BsB + n * 64 + quad * 16);
    }
    for (int im = 0; im < 4; ++im)
      for (int jn = 0; jn < 4; ++jn)
        acc[im][jn] = __builtin_amdgcn_mfma_f32_16x16x32_bf16(af[im], bfv[jn], acc[im][jn], 0, 0, 0);
  }

  // C/D layout: col = lane&15, row = quad*4 + reg  (m89/m91 verified)
  for (int im = 0; im < 4; ++im)
    for (int jn = 0; jn < 4; ++jn)
      for (int r = 0; r < 4; ++r) {
        int row = m0 + wm + im * 16 + quad * 4 + r;
        int col = n0 + wn + jn * 16 + l15;
        if constexpr (__is_same(OutT, float))
          C[(size_t)row * N + col] = acc[im][jn][r];
        else
          C[(size_t)row * N + col] = f2bf(acc[im][jn][r]);
      }
}

// ---------------------------------------------------------------------------
// RoPE (interleaved pairs) + scatter into Q[b][h][s][d] (token order) and
// paged K/V caches [blk][kvh][off][d] honoring block_tables.
// xqkv row layout: [0,2048)=Q heads, [2048,3072)=K heads, [3072,4096)=V heads.
// ---------------------------------------------------------------------------
__global__ __launch_bounds__(256) void rope_scatter(const u16* __restrict__ xqkv,
                                                    const int* __restrict__ positions,
                                                    const int* __restrict__ btab,
                                                    u16* __restrict__ qb,
                                                    u16* __restrict__ kb,
                                                    u16* __restrict__ vbuf) {
  int t = blockIdx.x;
  int tid = threadIdx.x;
  int b = t >> 10, srow = t & 1023;
  int pos = positions[t];
  int blk = btab[b * (SEQ / BLKSZ) + (pos >> 4)];
  int off = pos & (BLKSZ - 1);
  int c0 = tid * 16;

  struct __align__(16) { uint4 a, bq; } vv, oo;
  const u16* src = xqkv + (size_t)t * 4096 + c0;
  vv.a  = *(const uint4*)src;
  vv.bq = *(const uint4*)(src + 8);
  const u16* v = (const u16*)&vv;
  u16* o = (u16*)&oo;

  if (c0 < 3072) {  // Q or K section: apply RoPE on (even,odd) pairs
    int dbase = c0 & 127;
    float fpos = (float)pos;
    for (int j = 0; j < 8; ++j) {
      int i = (dbase >> 1) + j;                       // freq index 0..63
      float inv = exp2f(-(float)i * (13.287712379549449f / 64.0f)); // 10000^(-i/64)
      float ang = fpos * inv;
      float sn, cs;
      sincosf(ang, &sn, &cs);
      float fr = bf2f(v[2 * j]), fi = bf2f(v[2 * j + 1]);
      o[2 * j]     = f2bf(fr * cs - fi * sn);
      o[2 * j + 1] = f2bf(fr * sn + fi * cs);
    }
  } else {
    for (int j = 0; j < 16; ++j) o[j] = v[j];
  }

  u16* dst;
  if (c0 < 2048) {
    int head = c0 >> 7, d0 = c0 & 127;
    dst = qb + (((size_t)(b * NH + head)) * SEQ + srow) * HD + d0;
  } else if (c0 < 3072) {
    int cc = c0 - 2048;
    int kvh = cc >> 7, d0 = cc & 127;
    dst = kb + (((size_t)(blk * NKV + kvh) * BLKSZ + off)) * HD + d0;
  } else {
    int cc = c0 - 3072;
    int kvh = cc >> 7, d0 = cc & 127;
    dst = vbuf + (((size_t)(blk * NKV + kvh) * BLKSZ + off)) * HD + d0;
  }
  *(uint4*)dst = oo.a;
  *(uint4*)(dst + 8) = oo.bq;
}

// ---------------------------------------------------------------------------
// Flash attention over the paged cache: block = (64 q-rows, one (b,h)),
// 4 waves x 16 q-rows. KV tiles of 32 tokens (= 2 cache blocks).
// QK^T and PV via mfma 16x16x32; online softmax with 16-lane shfl_xor;
// P routed through per-wave LDS (C-layout -> A-layout, m120-verified);
// V staged transposed in LDS. Finite mask sentinel keeps exp2 args bounded.
// ---------------------------------------------------------------------------
__global__ __launch_bounds__(256) void attn_kernel(const u16* __restrict__ Q,
                                                   const u16* __restrict__ Kc,
                                                   const u16* __restrict__ Vc,
                                                   const int* __restrict__ positions,
                                                   const int* __restrict__ btab,
                                                   u16* __restrict__ O) {
  __shared__ __align__(16) u16 Ks[32 * 128];   // [tok][d]
  __shared__ __align__(16) u16 Vt[128 * 32];   // [d][tok]
  __shared__ __align__(16) u16 Ps[4 * 16 * 32];// per-wave P buffer [q][tok]
  const float SM_SCALE = 0.08838834764831845f; // 1/sqrt(128)
  const float LOG2E    = 1.4426950408889634f;
  const float NEGBIG   = -30000.0f;

  int tid = threadIdx.x;
  int wave = tid >> 6, lane = tid & 63, quad = lane >> 4, l15 = lane & 15;
  int bh = blockIdx.y;
  int b = bh >> 4, h = bh & 15, kvh = h >> 1;
  int q0 = blockIdx.x * 64;
  int qw = q0 + wave * 16;

  const u16* Qbase = Q + ((size_t)bh * SEQ + qw) * HD;
  const int* btrow = btab + b * (SEQ / BLKSZ);

  // Q fragments (A-layout: m=lane&15, k=quad*8+j), 4 k-blocks of 32
  bfrag aq[4];
  for (int kb2 = 0; kb2 < 4; ++kb2)
    aq[kb2] = *(const bfrag*)(Qbase + (size_t)l15 * HD + kb2 * 32 + quad * 8);

  int qpos[4];
  for (int r = 0; r < 4; ++r)
    qpos[r] = positions[(size_t)b * SEQ + qw + quad * 4 + r];

  f32x4 oa[8];
  for (int jd = 0; jd < 8; ++jd) oa[jd] = (f32x4){0.f, 0.f, 0.f, 0.f};
  float m_i[4] = {NEGBIG, NEGBIG, NEGBIG, NEGBIG};
  float l_i[4] = {0.f, 0.f, 0.f, 0.f};

  char* KsB = (char*)Ks;
  char* VtB = (char*)Vt;
  char* myPsB = (char*)(Ps + wave * 512);      // 512 u16 = 1024 B per wave

  // V staging decode
  int tokp = (tid & 15) * 2;
  int vd0 = (tid >> 4) * 8;

  int kend = q0 + 64;
  for (int kt = 0; kt < kend; kt += 32) {
    // paged lookup: tile spans exactly two 16-token cache blocks
    int blkA = btrow[(kt >> 4)], blkB = btrow[(kt >> 4) + 1];
    const u16* KbA = Kc + ((size_t)(blkA * NKV + kvh) * BLKSZ) * HD;
    const u16* KbB = Kc + ((size_t)(blkB * NKV + kvh) * BLKSZ) * HD;
    const u16* VbA = Vc + ((size_t)(blkA * NKV + kvh) * BLKSZ) * HD;
    const u16* VbB = Vc + ((size_t)(blkB * NKV + kvh) * BLKSZ) * HD;

    __syncthreads();
    asm volatile("" ::: "memory");
    // K tile: 512 granules of 16B, straight [tok][d] layout
    for (int ii = 0; ii < 2; ++ii) {
      int g = tid + ii * 256;
      int row = g >> 4, dg = g & 15;
      const u16* kb_src = (row < 16) ? (KbA + (size_t)row * HD)
                                     : (KbB + (size_t)(row - 16) * HD);
      *(uint4*)(KsB + g * 16) = *(const uint4*)(kb_src + dg * 8);
    }
    // V tile transposed: Vt[d][tok]; tokens tokp, tokp+1 (same half)
    {
      const u16* vb_src = (tokp < 16) ? (VbA + (size_t)tokp * HD)
                                      : (VbB + (size_t)(tokp - 16) * HD);
      uint4 r0 = *(const uint4*)(vb_src + vd0);
      uint4 r1 = *(const uint4*)(vb_src + HD + vd0);
      const u16* p0 = (const u16*)&r0;
      const u16* p1 = (const u16*)&r1;
      for (int jj = 0; jj < 8; ++jj) {
        int d = vd0 + jj;
        unsigned int val = (unsigned int)p0[jj] | ((unsigned int)p1[jj] << 16);
        *(unsigned int*)(VtB + d * 64 + tokp * 2) = val;
      }
    }
    hard_fence();
    __syncthreads();

    if (kt <= qw + 15) {  // wave-uniform: skip fully-masked tiles for this wave
      // S = Q K^T  (16 q x 32 tok)
      f32x4 sa[2];
      sa[0] = (f32x4){0.f, 0.f, 0.f, 0.f};
      sa[1] = (f32x4){0.f, 0.f, 0.f, 0.f};
      for (int jn = 0; jn < 2; ++jn) {
        int tok = jn * 16 + l15;
        for (int kb2 = 0; kb2 < 4; ++kb2) {
          bfrag bk = *(const bfrag*)(KsB + tok * 256 + (kb2 * 4 + quad) * 16);
          sa[jn] = __builtin_amdgcn_mfma_f32_16x16x32_bf16(aq[kb2], bk, sa[jn], 0, 0, 0);
        }
      }
      // online softmax (rows q = quad*4+r; cols across the 16 lanes of the quad)
      float pr0[4], pr1[4], alpha[4];
      for (int r = 0; r < 4; ++r) {
        float s0 = sa[0][r] * SM_SCALE;
        float s1 = sa[1][r] * SM_SCALE;
        if (kt + l15 > qpos[r]) s0 = NEGBIG;
        if (kt + 16 + l15 > qpos[r]) s1 = NEGBIG;
        float mx = fmaxf(s0, s1);
        mx = fmaxf(mx, __shfl_xor(mx, 1, 64));
        mx = fmaxf(mx, __shfl_xor(mx, 2, 64));
        mx = fmaxf(mx, __shfl_xor(mx, 4, 64));
        mx = fmaxf(mx, __shfl_xor(mx, 8, 64));
        float mnew = fmaxf(m_i[r], mx);
        float al = exp2f((m_i[r] - mnew) * LOG2E);
        float p0 = exp2f((s0 - mnew) * LOG2E);
        float p1 = exp2f((s1 - mnew) * LOG2E);
        float rs = p0 + p1;
        rs += __shfl_xor(rs, 1, 64);
        rs += __shfl_xor(rs, 2, 64);
        rs += __shfl_xor(rs, 4, 64);
        rs += __shfl_xor(rs, 8, 64);
        l_i[r] = l_i[r] * al + rs;
        m_i[r] = mnew;
        alpha[r] = al;
        pr0[r] = p0; pr1[r] = p1;
      }
      for (int jd = 0; jd < 8; ++jd) {
        oa[jd][0] *= alpha[0];
        oa[jd][1] *= alpha[1];
        oa[jd][2] *= alpha[2];
        oa[jd][3] *= alpha[3];
      }
      // P: C-layout -> A-layout via per-wave LDS [q][tok] (straight)
      for (int r = 0; r < 4; ++r) {
        int q = quad * 4 + r;
        *(u16*)(myPsB + q * 64 + l15 * 2)        = f2bf(pr0[r]);
        *(u16*)(myPsB + q * 64 + (16 + l15) * 2) = f2bf(pr1[r]);
      }
      bfrag ap = *(const bfrag*)(myPsB + l15 * 64 + quad * 16);
      // O += P V   (K-dim = 32 tokens = one mfma per 16-d block)
      for (int jd = 0; jd < 8; ++jd) {
        int d = jd * 16 + l15;
        bfrag bv = *(const bfrag*)(VtB + d * 64 + quad * 16);
        oa[jd] = __builtin_amdgcn_mfma_f32_16x16x32_bf16(ap, bv, oa[jd], 0, 0, 0);
      }
    }
  }

  // normalize + write O[token][h*128+d] (input A of the output GEMM)
  for (int r = 0; r < 4; ++r) {
    float inv = 1.0f / fmaxf(l_i[r], 1e-30f);
    size_t trow = (size_t)b * SEQ + qw + quad * 4 + r;
    for (int jd = 0; jd < 8; ++jd)
      O[trow * 2048 + (size_t)h * HD + jd * 16 + l15] = f2bf(oa[jd][r] * inv);
  }
}

// ---------------------------------------------------------------------------
extern "C" void kernel_launch(void* const* d_in, const int* in_sizes, int n_in,
                              void* d_out, int out_size, void* d_ws, size_t ws_size,
                              hipStream_t stream) {
  (void)in_sizes; (void)n_in; (void)out_size;
  const float* xf  = (const float*)d_in[0];
  const float* wqf = (const float*)d_in[1];
  const float* wkf = (const float*)d_in[2];
  const float* wvf = (const float*)d_in[3];
  const float* wof = (const float*)d_in[4];
  const int* positions = (const int*)d_in[7];
  const int* btab      = (const int*)d_in[10];
  float* out = (float*)d_out;

  // workspace carve-up (bf16 elements). woT FIRST so the obuf fallback
  // (aliasing wqkvT+xbf) can never clobber it.
  u16* ws    = (u16*)d_ws;
  u16* woT   = ws;                                  // [2048][2048]
  u16* wqkvT = woT + (size_t)2048 * 2048;           // [4096][2048]  (wq^T|wk^T|wv^T)
  u16* xbf   = wqkvT + (size_t)4096 * 2048;         // [8192][2048]
  u16* xqkv  = xbf + (size_t)8192 * 2048;           // [8192][4096]
  u16* qb    = xqkv + (size_t)8192 * 4096;          // [8][16][1024][128]
  u16* kbuf  = qb + (size_t)8192 * 2048;            // [512][8][16][128] paged
  u16* vbuf  = kbuf + (size_t)8192 * 1024;          // [512][8][16][128] paged
  u16* wsend = vbuf + (size_t)8192 * 1024;

  size_t base_elems = (size_t)(wsend - ws);
  size_t obuf_elems = (size_t)8192 * 2048;
  u16* obuf;
  if (ws_size >= (base_elems + obuf_elems) * sizeof(u16))
    obuf = wsend;                                    // dedicated region
  else
    obuf = wqkvT;                                    // alias dead wqkvT+xbf span

  if (ws_size < base_elems * sizeof(u16)) return;    // insufficient scratch

  // 1) convert x to bf16; transpose+convert weights into B^T layout
  f32_to_bf16<<<dim3(8192), 256, 0, stream>>>(xf, xbf, (size_t)8192 * 2048);
  ktranspose_f<<<dim3(32, 32), 256, 0, stream>>>(wqf, wqkvT, 2048, 2048);
  ktranspose_f<<<dim3(16, 32), 256, 0, stream>>>(wkf, wqkvT + (size_t)2048 * 2048, 2048, 1024);
  ktranspose_f<<<dim3(16, 32), 256, 0, stream>>>(wvf, wqkvT + (size_t)3072 * 2048, 2048, 1024);
  ktranspose_f<<<dim3(32, 32), 256, 0, stream>>>(wof, woT, 2048, 2048);
  // 2) fused QKV projection: [8192,2048] @ [2048,4096] -> bf16
  gemm_bt<u16><<<dim3(32, 64), 256, 0, stream>>>(xbf, wqkvT, xqkv, 8192, 4096, 2048);
  // 3) RoPE + scatter into Q buffer and paged K/V caches
  rope_scatter<<<dim3(8192), 256, 0, stream>>>(xqkv, positions, btab, qb, kbuf, vbuf);
  // 4) causal GQA flash attention over the paged cache
  attn_kernel<<<dim3(16, 128), 256, 0, stream>>>(qb, kbuf, vbuf, positions, btab, obuf);
  // 5) output projection: [8192,2048] @ [2048,2048] -> fp32 out
  gemm_bt<float><<<dim3(16, 64), 256, 0, stream>>>(obuf, woT, out, 8192, 2048, 2048);
}

// Round 6
// 664.731 us; speedup vs baseline: 1.2157x; 1.2157x over previous
//
#include <hip/hip_runtime.h>
#include <stdint.h>

// Problem constants (Attention_39556648796173)
// Inputs: float32 buffers (per reference dtypes). Output: float32.
// Compute core: bf16 MFMA (comparison tolerance is bf16-scaled: 2% of max).
#define TTOK  8192
#define DIMM  2048
#define NH    16
#define NKV   8
#define HD    128
#define SEQ   1024
#define BATCH 8
#define BLKSZ 16

typedef unsigned short u16;
typedef __attribute__((ext_vector_type(8))) short bfrag;   // 8 x bf16 (4 VGPRs)
typedef __attribute__((ext_vector_type(4))) float f32x4;   // MFMA accumulator

__device__ __forceinline__ float bf2f(u16 u) {
  unsigned int v = ((unsigned int)u) << 16;
  float f; __builtin_memcpy(&f, &v, 4); return f;
}
__device__ __forceinline__ u16 f2bf(float f) {
  unsigned int v; __builtin_memcpy(&v, &f, 4);
  v = v + 0x7FFFu + ((v >> 16) & 1u);   // RNE
  return (u16)(v >> 16);
}

// async global->LDS, 16B per lane; LDS dest = wave-uniform base + lane*16
__device__ __forceinline__ void gll16(const void* g, void* l) {
  __builtin_amdgcn_global_load_lds(
      (__attribute__((address_space(1))) void*)(g),
      (__attribute__((address_space(3))) void*)(l), 16, 0, 0);
}
// full drain (vmcnt=0, expcnt=0, lgkmcnt=0) + compiler memory fence
// (needed only around gll16 DMA staging — fixed the round-3 warm-call hazard)
__device__ __forceinline__ void hard_fence() {
  asm volatile("" ::: "memory");
  __builtin_amdgcn_s_waitcnt(0);
  asm volatile("" ::: "memory");
}

// ---------------------------------------------------------------------------
// fp32 -> bf16 bulk convert (n multiple of 2048); 8 elems/thread
// ---------------------------------------------------------------------------
__global__ __launch_bounds__(256) void f32_to_bf16(const float* __restrict__ in,
                                                   u16* __restrict__ out, size_t n) {
  size_t i = ((size_t)blockIdx.x * 256 + threadIdx.x) * 8;
  if (i >= n) return;
  float4 a = *(const float4*)(in + i);
  float4 b = *(const float4*)(in + i + 4);
  union { u16 o[8]; uint4 v; } u;
  u.o[0] = f2bf(a.x); u.o[1] = f2bf(a.y); u.o[2] = f2bf(a.z); u.o[3] = f2bf(a.w);
  u.o[4] = f2bf(b.x); u.o[5] = f2bf(b.y); u.o[6] = f2bf(b.z); u.o[7] = f2bf(b.w);
  *(uint4*)(out + i) = u.v;
}

// ---------------------------------------------------------------------------
// Tiled transpose + fp32->bf16: out[n][k] = bf16(in[k][n]), K,N multiples of 64
// ---------------------------------------------------------------------------
__global__ __launch_bounds__(256) void ktranspose_f(const float* __restrict__ in,
                                                    u16* __restrict__ out, int K, int N) {
  __shared__ __align__(16) u16 tile[64 * 65];
  int n0 = blockIdx.x * 64, k0 = blockIdx.y * 64;
  int tx = threadIdx.x & 63, ty = threadIdx.x >> 6;
  for (int r = 0; r < 16; ++r) {
    int kk = r * 4 + ty;
    tile[kk * 65 + tx] = f2bf(in[(size_t)(k0 + kk) * N + n0 + tx]);
  }
  __syncthreads();
  for (int r = 0; r < 16; ++r) {
    int nn = r * 4 + ty;
    out[(size_t)(n0 + nn) * K + k0 + tx] = tile[tx * 65 + nn];
  }
}

// ---------------------------------------------------------------------------
// m97-style GEMM: C[M,N] = A[M,K] @ B, with B given transposed (Bt[N,K]).
// 128x128 tile, BK=32, 4 waves (2x2 of 64x64), mfma 16x16x32 bf16.
// Hardened: explicit full s_waitcnt + compiler fences around the gll16 DMA.
// ---------------------------------------------------------------------------
template <typename OutT>
__global__ __launch_bounds__(256) void gemm_bt(const u16* __restrict__ A,
                                               const u16* __restrict__ Bt,
                                               OutT* __restrict__ C,
                                               int M, int N, int K) {
  __shared__ __align__(16) u16 As[128 * 32];
  __shared__ __align__(16) u16 Bs[128 * 32];
  int tid = threadIdx.x;
  int wave = tid >> 6, lane = tid & 63, quad = lane >> 4, l15 = lane & 15;
  int m0 = blockIdx.y * 128, n0 = blockIdx.x * 128;
  int wm = (wave >> 1) * 64, wn = (wave & 1) * 64;

  f32x4 acc[4][4];
  for (int i = 0; i < 4; ++i)
    for (int j = 0; j < 4; ++j) acc[i][j] = (f32x4){0.f, 0.f, 0.f, 0.f};

  // staging decode: straight mapping (granule g -> row g>>2, k-granule g&3)
  int g0 = wave * 64 + lane;            // granules 0..255
  int g1 = 256 + wave * 64 + lane;      // granules 256..511
  const u16* Arow0 = A + (size_t)(m0 + (g0 >> 2)) * K + (g0 & 3) * 8;
  const u16* Arow1 = A + (size_t)(m0 + (g1 >> 2)) * K + (g1 & 3) * 8;
  const u16* Brow0 = Bt + (size_t)(n0 + (g0 >> 2)) * K + (g0 & 3) * 8;
  const u16* Brow1 = Bt + (size_t)(n0 + (g1 >> 2)) * K + (g1 & 3) * 8;
  char* AsB = (char*)As;
  char* BsB = (char*)Bs;
  int lds0 = wave * 1024, lds1 = 4096 + wave * 1024;  // wave-uniform bases

  for (int k0 = 0; k0 < K; k0 += 32) {
    __syncthreads();                 // all waves done reading previous tile
    asm volatile("" ::: "memory");   // no staging op may move above this point
    gll16(Arow0 + k0, AsB + lds0);
    gll16(Arow1 + k0, AsB + lds1);
    gll16(Brow0 + k0, BsB + lds0);
    gll16(Brow1 + k0, BsB + lds1);
    hard_fence();                    // own DMA fully landed in LDS
    __syncthreads();                 // everyone's DMA landed

    bfrag af[4], bfv[4];
    for (int im = 0; im < 4; ++im) {
      int m = wm + im * 16 + l15;
      af[im] = *(const bfrag*)(AsB + m * 64 + quad * 16);
    }
    for (int jn = 0; jn < 4; ++jn) {
      int n = wn + jn * 16 + l15;
      bfv[jn] = *(const bfrag*)(BsB + n * 64 + quad * 16);
    }
    for (int im = 0; im < 4; ++im)
      for (int jn = 0; jn < 4; ++jn)
        acc[im][jn] = __builtin_amdgcn_mfma_f32_16x16x32_bf16(af[im], bfv[jn], acc[im][jn], 0, 0, 0);
  }

  // C/D layout: col = lane&15, row = quad*4 + reg  (m89/m91 verified)
  for (int im = 0; im < 4; ++im)
    for (int jn = 0; jn < 4; ++jn)
      for (int r = 0; r < 4; ++r) {
        int row = m0 + wm + im * 16 + quad * 4 + r;
        int col = n0 + wn + jn * 16 + l15;
        if constexpr (__is_same(OutT, float))
          C[(size_t)row * N + col] = acc[im][jn][r];
        else
          C[(size_t)row * N + col] = f2bf(acc[im][jn][r]);
      }
}

// ---------------------------------------------------------------------------
// RoPE (interleaved pairs) + scatter into Q[b][h][s][d] (token order) and
// paged K/V caches [blk][kvh][off][d] honoring block_tables.
// xqkv row layout: [0,2048)=Q heads, [2048,3072)=K heads, [3072,4096)=V heads.
// ---------------------------------------------------------------------------
__global__ __launch_bounds__(256) void rope_scatter(const u16* __restrict__ xqkv,
                                                    const int* __restrict__ positions,
                                                    const int* __restrict__ btab,
                                                    u16* __restrict__ qb,
                                                    u16* __restrict__ kb,
                                                    u16* __restrict__ vbuf) {
  int t = blockIdx.x;
  int tid = threadIdx.x;
  int b = t >> 10, srow = t & 1023;
  int pos = positions[t];
  int blk = btab[b * (SEQ / BLKSZ) + (pos >> 4)];
  int off = pos & (BLKSZ - 1);
  int c0 = tid * 16;

  struct __align__(16) { uint4 a, bq; } vv, oo;
  const u16* src = xqkv + (size_t)t * 4096 + c0;
  vv.a  = *(const uint4*)src;
  vv.bq = *(const uint4*)(src + 8);
  const u16* v = (const u16*)&vv;
  u16* o = (u16*)&oo;

  if (c0 < 3072) {  // Q or K section: apply RoPE on (even,odd) pairs
    int dbase = c0 & 127;
    float fpos = (float)pos;
    for (int j = 0; j < 8; ++j) {
      int i = (dbase >> 1) + j;                       // freq index 0..63
      float inv = exp2f(-(float)i * (13.287712379549449f / 64.0f)); // 10000^(-i/64)
      float ang = fpos * inv;
      float sn, cs;
      sincosf(ang, &sn, &cs);
      float fr = bf2f(v[2 * j]), fi = bf2f(v[2 * j + 1]);
      o[2 * j]     = f2bf(fr * cs - fi * sn);
      o[2 * j + 1] = f2bf(fr * sn + fi * cs);
    }
  } else {
    for (int j = 0; j < 16; ++j) o[j] = v[j];
  }

  u16* dst;
  if (c0 < 2048) {
    int head = c0 >> 7, d0 = c0 & 127;
    dst = qb + (((size_t)(b * NH + head)) * SEQ + srow) * HD + d0;
  } else if (c0 < 3072) {
    int cc = c0 - 2048;
    int kvh = cc >> 7, d0 = cc & 127;
    dst = kb + (((size_t)(blk * NKV + kvh) * BLKSZ + off)) * HD + d0;
  } else {
    int cc = c0 - 3072;
    int kvh = cc >> 7, d0 = cc & 127;
    dst = vbuf + (((size_t)(blk * NKV + kvh) * BLKSZ + off)) * HD + d0;
  }
  *(uint4*)dst = oo.a;
  *(uint4*)(dst + 8) = oo.bq;
}

// ---------------------------------------------------------------------------
// Flash attention v2 over the paged cache.
// Block = (128 q-rows, one (b,h)); 4 waves; each wave owns 32 q-rows as two
// 16-row sub-blocks. KV tiles of 32 tokens (= 2 cache blocks).
// LDS strides padded off powers of two (Ks 272 B, Vt/Ps 80 B) so all b128
// reads are <=2-way bank-aliased (free, m136). Plain ds_write staging (no DMA
// -> no hard fence needed; barriers only).
// ---------------------------------------------------------------------------
#define KS_STRIDE 272   // bytes per K token row (128*2 + 16 pad)
#define VT_STRIDE 80    // bytes per V d row (32*2 + 16 pad)
#define PS_STRIDE 80    // bytes per P q row (32*2 + 16 pad)

__global__ __launch_bounds__(256) void attn_kernel(const u16* __restrict__ Q,
                                                   const u16* __restrict__ Kc,
                                                   const u16* __restrict__ Vc,
                                                   const int* __restrict__ positions,
                                                   const int* __restrict__ btab,
                                                   u16* __restrict__ O) {
  __shared__ __align__(16) u16 Ks[32 * (KS_STRIDE / 2)];      // [tok][d] padded
  __shared__ __align__(16) u16 Vt[128 * (VT_STRIDE / 2)];     // [d][tok] padded
  __shared__ __align__(16) u16 Ps[4 * 2 * 16 * (PS_STRIDE / 2)]; // [wave][im][q][tok]
  const float SM_SCALE = 0.08838834764831845f; // 1/sqrt(128)
  const float LOG2E    = 1.4426950408889634f;
  const float NEGBIG   = -30000.0f;

  int tid = threadIdx.x;
  int wave = tid >> 6, lane = tid & 63, quad = lane >> 4, l15 = lane & 15;
  int bh = blockIdx.x;
  int b = bh >> 4, h = bh & 15, kvh = h >> 1;
  int q0 = blockIdx.y * 128;
  int qw = q0 + wave * 32;                     // this wave's 32 rows

  const u16* Qbase = Q + ((size_t)bh * SEQ + qw) * HD;
  const int* btrow = btab + b * (SEQ / BLKSZ);

  // Q fragments (A-layout: m=lane&15, k=quad*8+j): 2 sub-blocks x 4 k-blocks
  bfrag aq[2][4];
#pragma unroll
  for (int im = 0; im < 2; ++im)
#pragma unroll
    for (int kb2 = 0; kb2 < 4; ++kb2)
      aq[im][kb2] = *(const bfrag*)(Qbase + (size_t)(im * 16 + l15) * HD + kb2 * 32 + quad * 8);

  int qpos[2][4];
#pragma unroll
  for (int im = 0; im < 2; ++im)
#pragma unroll
    for (int r = 0; r < 4; ++r)
      qpos[im][r] = positions[(size_t)b * SEQ + qw + im * 16 + quad * 4 + r];

  f32x4 oa[2][8];
#pragma unroll
  for (int im = 0; im < 2; ++im)
#pragma unroll
    for (int jd = 0; jd < 8; ++jd) oa[im][jd] = (f32x4){0.f, 0.f, 0.f, 0.f};
  float m_i[2][4], l_i[2][4];
#pragma unroll
  for (int im = 0; im < 2; ++im)
#pragma unroll
    for (int r = 0; r < 4; ++r) { m_i[im][r] = NEGBIG; l_i[im][r] = 0.f; }

  char* KsB = (char*)Ks;
  char* VtB = (char*)Vt;

  // V staging decode
  int tokp = (tid & 15) * 2;
  int vd0 = (tid >> 4) * 8;

  int kend = q0 + 128;
  for (int kt = 0; kt < kend; kt += 32) {
    // paged lookup: tile spans exactly two 16-token cache blocks
    int blkA = btrow[(kt >> 4)], blkB = btrow[(kt >> 4) + 1];
    const u16* KbA = Kc + ((size_t)(blkA * NKV + kvh) * BLKSZ) * HD;
    const u16* KbB = Kc + ((size_t)(blkB * NKV + kvh) * BLKSZ) * HD;
    const u16* VbA = Vc + ((size_t)(blkA * NKV + kvh) * BLKSZ) * HD;
    const u16* VbB = Vc + ((size_t)(blkB * NKV + kvh) * BLKSZ) * HD;

    __syncthreads();
    // K tile: 512 granules of 16B into padded [tok][d]
#pragma unroll
    for (int ii = 0; ii < 2; ++ii) {
      int g = tid + ii * 256;
      int row = g >> 4, dg = g & 15;
      const u16* kb_src = (row < 16) ? (KbA + (size_t)row * HD)
                                     : (KbB + (size_t)(row - 16) * HD);
      *(uint4*)(KsB + row * KS_STRIDE + dg * 16) = *(const uint4*)(kb_src + dg * 8);
    }
    // V tile transposed into padded [d][tok]; tokens tokp, tokp+1 (same half)
    {
      const u16* vb_src = (tokp < 16) ? (VbA + (size_t)tokp * HD)
                                      : (VbB + (size_t)(tokp - 16) * HD);
      uint4 r0 = *(const uint4*)(vb_src + vd0);
      uint4 r1 = *(const uint4*)(vb_src + HD + vd0);
      const u16* p0 = (const u16*)&r0;
      const u16* p1 = (const u16*)&r1;
#pragma unroll
      for (int jj = 0; jj < 8; ++jj) {
        int d = vd0 + jj;
        unsigned int val = (unsigned int)p0[jj] | ((unsigned int)p1[jj] << 16);
        *(unsigned int*)(VtB + d * VT_STRIDE + tokp * 2) = val;
      }
    }
    __syncthreads();

#pragma unroll
    for (int im = 0; im < 2; ++im) {
      if (kt > qw + im * 16 + 15) continue;  // wave-uniform skip (fully masked)
      // S = Q K^T  (16 q x 32 tok)
      f32x4 sa[2];
      sa[0] = (f32x4){0.f, 0.f, 0.f, 0.f};
      sa[1] = (f32x4){0.f, 0.f, 0.f, 0.f};
#pragma unroll
      for (int jn = 0; jn < 2; ++jn) {
        int tok = jn * 16 + l15;
#pragma unroll
        for (int kb2 = 0; kb2 < 4; ++kb2) {
          bfrag bk = *(const bfrag*)(KsB + tok * KS_STRIDE + (kb2 * 4 + quad) * 16);
          sa[jn] = __builtin_amdgcn_mfma_f32_16x16x32_bf16(aq[im][kb2], bk, sa[jn], 0, 0, 0);
        }
      }
      // online softmax (rows q = quad*4+r; cols across the 16 lanes of the quad)
      float pr0[4], pr1[4], alpha[4];
#pragma unroll
      for (int r = 0; r < 4; ++r) {
        float s0 = sa[0][r] * SM_SCALE;
        float s1 = sa[1][r] * SM_SCALE;
        if (kt + l15 > qpos[im][r]) s0 = NEGBIG;
        if (kt + 16 + l15 > qpos[im][r]) s1 = NEGBIG;
        float mx = fmaxf(s0, s1);
        mx = fmaxf(mx, __shfl_xor(mx, 1, 64));
        mx = fmaxf(mx, __shfl_xor(mx, 2, 64));
        mx = fmaxf(mx, __shfl_xor(mx, 4, 64));
        mx = fmaxf(mx, __shfl_xor(mx, 8, 64));
        float mnew = fmaxf(m_i[im][r], mx);
        float al = exp2f((m_i[im][r] - mnew) * LOG2E);
        float p0 = exp2f((s0 - mnew) * LOG2E);
        float p1 = exp2f((s1 - mnew) * LOG2E);
        float rs = p0 + p1;
        rs += __shfl_xor(rs, 1, 64);
        rs += __shfl_xor(rs, 2, 64);
        rs += __shfl_xor(rs, 4, 64);
        rs += __shfl_xor(rs, 8, 64);
        l_i[im][r] = l_i[im][r] * al + rs;
        m_i[im][r] = mnew;
        alpha[r] = al;
        pr0[r] = p0; pr1[r] = p1;
      }
#pragma unroll
      for (int jd = 0; jd < 8; ++jd) {
        oa[im][jd][0] *= alpha[0];
        oa[im][jd][1] *= alpha[1];
        oa[im][jd][2] *= alpha[2];
        oa[im][jd][3] *= alpha[3];
      }
      // P: C-layout -> A-layout via per-wave-per-subblock LDS region (padded)
      char* myPsB = (char*)Ps + (wave * 2 + im) * 16 * PS_STRIDE;
#pragma unroll
      for (int r = 0; r < 4; ++r) {
        int q = quad * 4 + r;
        *(u16*)(myPsB + q * PS_STRIDE + l15 * 2)        = f2bf(pr0[r]);
        *(u16*)(myPsB + q * PS_STRIDE + (16 + l15) * 2) = f2bf(pr1[r]);
      }
      bfrag ap = *(const bfrag*)(myPsB + l15 * PS_STRIDE + quad * 16);
      // O += P V   (K-dim = 32 tokens = one mfma per 16-d block)
#pragma unroll
      for (int jd = 0; jd < 8; ++jd) {
        int d = jd * 16 + l15;
        bfrag bv = *(const bfrag*)(VtB + d * VT_STRIDE + quad * 16);
        oa[im][jd] = __builtin_amdgcn_mfma_f32_16x16x32_bf16(ap, bv, oa[im][jd], 0, 0, 0);
      }
    }
  }

  // normalize + write O[token][h*128+d] (input A of the output GEMM)
#pragma unroll
  for (int im = 0; im < 2; ++im)
#pragma unroll
    for (int r = 0; r < 4; ++r) {
      float inv = 1.0f / fmaxf(l_i[im][r], 1e-30f);
      size_t trow = (size_t)b * SEQ + qw + im * 16 + quad * 4 + r;
#pragma unroll
      for (int jd = 0; jd < 8; ++jd)
        O[trow * 2048 + (size_t)h * HD + jd * 16 + l15] = f2bf(oa[im][jd][r] * inv);
    }
}

// ---------------------------------------------------------------------------
extern "C" void kernel_launch(void* const* d_in, const int* in_sizes, int n_in,
                              void* d_out, int out_size, void* d_ws, size_t ws_size,
                              hipStream_t stream) {
  (void)in_sizes; (void)n_in; (void)out_size;
  const float* xf  = (const float*)d_in[0];
  const float* wqf = (const float*)d_in[1];
  const float* wkf = (const float*)d_in[2];
  const float* wvf = (const float*)d_in[3];
  const float* wof = (const float*)d_in[4];
  const int* positions = (const int*)d_in[7];
  const int* btab      = (const int*)d_in[10];
  float* out = (float*)d_out;

  // workspace carve-up (bf16 elements). woT FIRST so the obuf fallback
  // (aliasing wqkvT+xbf) can never clobber it.
  u16* ws    = (u16*)d_ws;
  u16* woT   = ws;                                  // [2048][2048]
  u16* wqkvT = woT + (size_t)2048 * 2048;           // [4096][2048]  (wq^T|wk^T|wv^T)
  u16* xbf   = wqkvT + (size_t)4096 * 2048;         // [8192][2048]
  u16* xqkv  = xbf + (size_t)8192 * 2048;           // [8192][4096]
  u16* qb    = xqkv + (size_t)8192 * 4096;          // [8][16][1024][128]
  u16* kbuf  = qb + (size_t)8192 * 2048;            // [512][8][16][128] paged
  u16* vbuf  = kbuf + (size_t)8192 * 1024;          // [512][8][16][128] paged
  u16* wsend = vbuf + (size_t)8192 * 1024;

  size_t base_elems = (size_t)(wsend - ws);
  size_t obuf_elems = (size_t)8192 * 2048;
  u16* obuf;
  if (ws_size >= (base_elems + obuf_elems) * sizeof(u16))
    obuf = wsend;                                    // dedicated region
  else
    obuf = wqkvT;                                    // alias dead wqkvT+xbf span

  if (ws_size < base_elems * sizeof(u16)) return;    // insufficient scratch

  // 1) convert x to bf16; transpose+convert weights into B^T layout
  f32_to_bf16<<<dim3(8192), 256, 0, stream>>>(xf, xbf, (size_t)8192 * 2048);
  ktranspose_f<<<dim3(32, 32), 256, 0, stream>>>(wqf, wqkvT, 2048, 2048);
  ktranspose_f<<<dim3(16, 32), 256, 0, stream>>>(wkf, wqkvT + (size_t)2048 * 2048, 2048, 1024);
  ktranspose_f<<<dim3(16, 32), 256, 0, stream>>>(wvf, wqkvT + (size_t)3072 * 2048, 2048, 1024);
  ktranspose_f<<<dim3(32, 32), 256, 0, stream>>>(wof, woT, 2048, 2048);
  // 2) fused QKV projection: [8192,2048] @ [2048,4096] -> bf16
  gemm_bt<u16><<<dim3(32, 64), 256, 0, stream>>>(xbf, wqkvT, xqkv, 8192, 4096, 2048);
  // 3) RoPE + scatter into Q buffer and paged K/V caches
  rope_scatter<<<dim3(8192), 256, 0, stream>>>(xqkv, positions, btab, qb, kbuf, vbuf);
  // 4) causal GQA flash attention over the paged cache
  //    grid x = bh (128) for CU load balance across q-tiles, y = q-tile (8)
  attn_kernel<<<dim3(128, 8), 256, 0, stream>>>(qb, kbuf, vbuf, positions, btab, obuf);
  // 5) output projection: [8192,2048] @ [2048,2048] -> fp32 out
  gemm_bt<float><<<dim3(16, 64), 256, 0, stream>>>(obuf, woT, out, 8192, 2048, 2048);
}